// Round 1
// baseline (1514.778 us; speedup 1.0000x reference)
//
#include <hip/hip_runtime.h>
#include <hip/hip_bf16.h>
#include <math.h>

// Problem constants
#define HIDN  4096
#define NH    32
#define HD    128
#define NB    4
#define NT    16
#define MM    64          // NB*NT rows in all small GEMMs
#define SPAST 4096
#define STOT  4112
#define NCHUNK 8
#define SCHUNK 514        // STOT / NCHUNK (4112 = 8*514)

// ws layout (float offsets)
#define WS_Q    0
#define WS_CTX  262144
#define WS_PART 524288
#define PART_STRIDE 2080  // 16*128 o + 16 m + 16 l

typedef float f32x4 __attribute__((ext_vector_type(4)));
typedef short bf16x8 __attribute__((ext_vector_type(8)));  // 8 bf16 (guide-verified frag type)

__device__ __forceinline__ bf16x8 load_bf16x8(const float* p) {
    const float4* p4 = (const float4*)p;
    float4 a = p4[0], b = p4[1];
    float f[8] = {a.x, a.y, a.z, a.w, b.x, b.y, b.z, b.w};
    union { unsigned short u[8]; bf16x8 v; } r;
#pragma unroll
    for (int i = 0; i < 8; ++i) {
        unsigned int x = __float_as_uint(f[i]);
        // round-to-nearest-even bf16
        r.u[i] = (unsigned short)((x + 0x7FFFu + ((x >> 16) & 1u)) >> 16);
    }
    return r.v;
}

// C = A(64xK) @ W(NxK)^T  via bf16 MFMA, fp32 accum.
// blockIdx.y selects (W, C, mode): y==0 -> plain row-major C[m*4096+n]
// y>0 -> scatter into kv-cache layout [b,h,SPAST+t,d]
__global__ __launch_bounds__(256) void gemm64_kernel(
    const float* __restrict__ A,
    const float* __restrict__ w0, const float* __restrict__ w1, const float* __restrict__ w2,
    float* __restrict__ c0, float* __restrict__ c1, float* __restrict__ c2)
{
    const int wave = threadIdx.x >> 6;
    const int lane = threadIdx.x & 63;
    const int l16  = lane & 15;
    const int quad = lane >> 4;
    const int y = blockIdx.y;
    const float* W = (y == 0) ? w0 : (y == 1) ? w1 : w2;
    float*       C = (y == 0) ? c0 : (y == 1) ? c1 : c2;

    const int n = blockIdx.x * 64 + wave * 16 + l16;    // output column / W row
    const float* wrow  = W + (size_t)n * HIDN + quad * 8;
    const float* arow0 = A + (size_t)l16 * HIDN + quad * 8;

    f32x4 acc[4] = {};  // m-subtiles 0..3 (rows mi*16+..)
    for (int k0 = 0; k0 < HIDN; k0 += 32) {
        bf16x8 bfrag = load_bf16x8(wrow + k0);
#pragma unroll
        for (int mi = 0; mi < 4; ++mi) {
            bf16x8 afrag = load_bf16x8(arow0 + (size_t)mi * 16 * HIDN + k0);
            acc[mi] = __builtin_amdgcn_mfma_f32_16x16x32_bf16(afrag, bfrag, acc[mi], 0, 0, 0);
        }
    }
    // C/D layout: col = lane&15, row = quad*4 + reg  [m89-verified]
#pragma unroll
    for (int mi = 0; mi < 4; ++mi) {
#pragma unroll
        for (int r = 0; r < 4; ++r) {
            int m = mi * 16 + quad * 4 + r;
            if (y == 0) {
                C[(size_t)m * HIDN + n] = acc[mi][r];
            } else {
                int b = m >> 4, t = m & 15, h = n >> 7, d = n & 127;
                C[((size_t)(b * NH + h) * STOT + SPAST + t) * HD + d] = acc[mi][r];
            }
        }
    }
}

// Copy cache_k/cache_v into k_full/v_full (past positions). float4 granules.
__global__ __launch_bounds__(256) void concat_copy_kernel(
    const float4* __restrict__ ck, float4* __restrict__ kf,
    const float4* __restrict__ cv, float4* __restrict__ vf)
{
    const float4* src = blockIdx.y ? cv : ck;
    float4*       dst = blockIdx.y ? vf : kf;
    const long long total = 16777216LL;  // 128 bh * 4096 s * 32 float4
    for (long long i = (long long)blockIdx.x * blockDim.x + threadIdx.x; i < total;
         i += (long long)gridDim.x * blockDim.x) {
        long long bh = i >> 17;            // / (4096*32)
        long long r  = i & 131071LL;
        dst[bh * 131584LL + r] = src[i];   // 4112*32 = 131584
    }
}

// Split-S flash attention partials. grid (128 bh, NCHUNK). 256 threads.
__global__ __launch_bounds__(256) void attn_partial_kernel(
    const float* __restrict__ qp,   // ws q_proj 64x4096
    const float* __restrict__ kf,   // k_full (in d_out)
    const float* __restrict__ vf,   // v_full (in d_out)
    float* __restrict__ part)
{
    __shared__ float qs[16][128];
    __shared__ float sc[16][257];
    __shared__ float red[16][16];
    __shared__ float m_run[16], l_run[16], alpha_s[16];

    const int tid = threadIdx.x;
    const int bh  = blockIdx.x;
    const int c   = blockIdx.y;
    const int b = bh >> 5, h = bh & 31;
    const int s_beg = c * SCHUNK, s_end = s_beg + SCHUNK;

    const float scale = 0.08838834764831845f;  // 1/sqrt(128)
    for (int i = tid; i < 16 * 128; i += 256) {
        int t = i >> 7, d = i & 127;
        qs[t][d] = qp[(size_t)(b * 16 + t) * HIDN + h * 128 + d] * scale;
    }
    if (tid < 16) { m_run[tid] = -INFINITY; l_run[tid] = 0.f; }
    __syncthreads();

    const int tg = tid >> 4;   // t owned in reduce/PV phases
    const int ig = tid & 15;
    float o_loc[8];
#pragma unroll
    for (int i = 0; i < 8; ++i) o_loc[i] = 0.f;

    for (int s0 = s_beg; s0 < s_end; s0 += 256) {
        const int tile_n = min(256, s_end - s0);
        // ---- scores: thread j owns s = s0+j
        if (tid < tile_n) {
            const float* krow = kf + ((size_t)bh * STOT + (s0 + tid)) * HD;
            float scr[16];
#pragma unroll
            for (int t = 0; t < 16; ++t) scr[t] = 0.f;
            for (int dc = 0; dc < 128; dc += 32) {
                float4 kb[8];
#pragma unroll
                for (int u = 0; u < 8; ++u) kb[u] = ((const float4*)(krow + dc))[u];
#pragma unroll
                for (int t = 0; t < 16; ++t) {
                    float s4 = 0.f;
#pragma unroll
                    for (int u = 0; u < 8; ++u) {
                        float4 qv = ((const float4*)&qs[t][dc])[u];
                        s4 += qv.x * kb[u].x + qv.y * kb[u].y + qv.z * kb[u].z + qv.w * kb[u].w;
                    }
                    scr[t] += s4;
                }
            }
#pragma unroll
            for (int t = 0; t < 16; ++t) sc[t][tid] = scr[t];
        }
        __syncthreads();
        // ---- per-t tile max
        {
            float pm = -INFINITY;
            for (int j = ig; j < tile_n; j += 16) pm = fmaxf(pm, sc[tg][j]);
            red[tg][ig] = pm;
        }
        __syncthreads();
        if (tid < 16) {
            float tmax = -INFINITY;
#pragma unroll
            for (int i = 0; i < 16; ++i) tmax = fmaxf(tmax, red[tid][i]);
            float mo = m_run[tid];
            float mn = fmaxf(mo, tmax);
            alpha_s[tid] = __expf(mo - mn);
            m_run[tid] = mn;
        }
        __syncthreads();
        // ---- exp + tile sum
        {
            float ps = 0.f;
            const float mn = m_run[tg];
            for (int j = ig; j < tile_n; j += 16) {
                float p = __expf(sc[tg][j] - mn);
                sc[tg][j] = p;
                ps += p;
            }
            red[tg][ig] = ps;
        }
        __syncthreads();
        if (tid < 16) {
            float ts = 0.f;
#pragma unroll
            for (int i = 0; i < 16; ++i) ts += red[tid][i];
            l_run[tid] = l_run[tid] * alpha_s[tid] + ts;
        }
        __syncthreads();
        // ---- rescale + PV: thread owns (t=tg, d=ig*8..ig*8+7)
        {
            const float al = alpha_s[tg];
#pragma unroll
            for (int i = 0; i < 8; ++i) o_loc[i] *= al;
            const float* vbase = vf + ((size_t)bh * STOT + s0) * HD + ig * 8;
            for (int j = 0; j < tile_n; ++j) {
                float p = sc[tg][j];
                const float4* vr = (const float4*)(vbase + (size_t)j * HD);
                float4 v0 = vr[0], v1 = vr[1];
                o_loc[0] += p * v0.x; o_loc[1] += p * v0.y;
                o_loc[2] += p * v0.z; o_loc[3] += p * v0.w;
                o_loc[4] += p * v1.x; o_loc[5] += p * v1.y;
                o_loc[6] += p * v1.z; o_loc[7] += p * v1.w;
            }
        }
        __syncthreads();   // sc reused next tile
    }
    float* pp = part + ((size_t)bh * NCHUNK + c) * PART_STRIDE;
#pragma unroll
    for (int i = 0; i < 8; ++i) pp[tg * 128 + ig * 8 + i] = o_loc[i];
    if (tid < 16) { pp[2048 + tid] = m_run[tid]; pp[2064 + tid] = l_run[tid]; }
}

// Merge NCHUNK partials -> ctx (64x4096 row-major in ws)
__global__ __launch_bounds__(256) void combine_kernel(
    const float* __restrict__ part, float* __restrict__ ctx)
{
    const int bh = blockIdx.x;
    const int tid = threadIdx.x;
    const int t = tid >> 4, i = tid & 15;
    const int b = bh >> 5, h = bh & 31;
    const float* pb = part + (size_t)bh * NCHUNK * PART_STRIDE;

    float M = -INFINITY;
#pragma unroll
    for (int cI = 0; cI < NCHUNK; ++cI) M = fmaxf(M, pb[cI * PART_STRIDE + 2048 + t]);
    float L = 0.f;
    float w[NCHUNK];
#pragma unroll
    for (int cI = 0; cI < NCHUNK; ++cI) {
        float e = __expf(pb[cI * PART_STRIDE + 2048 + t] - M);
        w[cI] = e;
        L += e * pb[cI * PART_STRIDE + 2064 + t];
    }
    const float invL = 1.f / L;
    float o[8];
#pragma unroll
    for (int k = 0; k < 8; ++k) o[k] = 0.f;
#pragma unroll
    for (int cI = 0; cI < NCHUNK; ++cI) {
        const float* po = pb + cI * PART_STRIDE + t * 128 + i * 8;
        const float wc = w[cI];
#pragma unroll
        for (int k = 0; k < 8; ++k) o[k] += wc * po[k];
    }
    float* dst = ctx + (size_t)(b * 16 + t) * HIDN + h * 128 + i * 8;
#pragma unroll
    for (int k = 0; k < 8; ++k) dst[k] = o[k] * invL;
}

extern "C" void kernel_launch(void* const* d_in, const int* in_sizes, int n_in,
                              void* d_out, int out_size, void* d_ws, size_t ws_size,
                              hipStream_t stream) {
    const float* hidden  = (const float*)d_in[0];
    const float* cache_k = (const float*)d_in[1];
    const float* cache_v = (const float*)d_in[2];
    const float* wq = (const float*)d_in[3];
    const float* wk = (const float*)d_in[4];
    const float* wv = (const float*)d_in[5];
    const float* wo = (const float*)d_in[6];

    float* out   = (float*)d_out;            // 64*4096
    float* kfull = out + 262144;             // 128*4112*128
    float* vfull = kfull + 67371008LL;

    float* ws   = (float*)d_ws;
    float* qp   = ws + WS_Q;
    float* ctx  = ws + WS_CTX;
    float* part = ws + WS_PART;

    // 1. QKV projections; K/V written directly into cache positions of k_full/v_full
    gemm64_kernel<<<dim3(64, 3), 256, 0, stream>>>(hidden, wq, wk, wv, qp, kfull, vfull);
    // 2. copy past cache into k_full/v_full
    concat_copy_kernel<<<dim3(4096, 2), 256, 0, stream>>>(
        (const float4*)cache_k, (float4*)kfull, (const float4*)cache_v, (float4*)vfull);
    // 3. split-S flash attention partials
    attn_partial_kernel<<<dim3(128, NCHUNK), 256, 0, stream>>>(qp, kfull, vfull, part);
    // 4. combine partials -> ctx
    combine_kernel<<<dim3(128), 256, 0, stream>>>(part, ctx);
    // 5. output projection
    gemm64_kernel<<<dim3(64, 1), 256, 0, stream>>>(ctx, wo, wo, wo, out, nullptr, nullptr);
}